// Round 1
// baseline (1080.772 us; speedup 1.0000x reference)
//
#include <hip/hip_runtime.h>
#include <cmath>

#define L_DIM 2048
#define C_CH  16
#define B_SZ  2
#define N_G   4
#define C_PG  4
#define K_SZ  11
#define PADK  5

#define TY 64
#define TX 32
#define HY (TY + K_SZ - 1)   /* 74 */
#define HX (TX + K_SZ - 1)   /* 42 */
#define PITCH 44             /* floats; 44%32=12 -> only 2-way bank alias (free) */

typedef _Float16 f16;

struct alignas(8) H4 { f16 x, y, z, w; };

// ---------------- causal softmax: one wave per row ----------------
__global__ __launch_bounds__(256) void softmax_rows_k(
    const float* __restrict__ scores, f16* __restrict__ probs) {
  const int wid  = (blockIdx.x << 2) + (threadIdx.x >> 6);  // global row id
  const int lane = threadIdx.x & 63;
  const int y    = wid & (L_DIM - 1);                        // row within map
  const float* srow = scores + (size_t)wid * L_DIM;

  float v[32];
#pragma unroll
  for (int j = 0; j < 8; ++j) {
    const int x = j * 256 + lane * 4;
    const float4 f = *reinterpret_cast<const float4*>(srow + x);
    v[4*j+0] = (x + 0 <= y) ? f.x : -INFINITY;
    v[4*j+1] = (x + 1 <= y) ? f.y : -INFINITY;
    v[4*j+2] = (x + 2 <= y) ? f.z : -INFINITY;
    v[4*j+3] = (x + 3 <= y) ? f.w : -INFINITY;
  }
  float m = v[0];
#pragma unroll
  for (int i = 1; i < 32; ++i) m = fmaxf(m, v[i]);
#pragma unroll
  for (int off = 32; off >= 1; off >>= 1) m = fmaxf(m, __shfl_xor(m, off, 64));

  float s = 0.f;
#pragma unroll
  for (int i = 0; i < 32; ++i) { v[i] = __expf(v[i] - m); s += v[i]; }
#pragma unroll
  for (int off = 32; off >= 1; off >>= 1) s += __shfl_xor(s, off, 64);
  const float inv = 1.0f / s;   // s >= 1 always (max element contributes 1)

  f16* prow = probs + (size_t)wid * L_DIM;
#pragma unroll
  for (int j = 0; j < 8; ++j) {
    const int x = j * 256 + lane * 4;
    H4 h;
    h.x = (f16)(v[4*j+0] * inv);
    h.y = (f16)(v[4*j+1] * inv);
    h.z = (f16)(v[4*j+2] * inv);
    h.w = (f16)(v[4*j+3] * inv);
    *reinterpret_cast<H4*>(prow + x) = h;   // upper triangle gets exact zeros
  }
}

// ---------------- grouped 11x11 conv over probs ----------------
// block: 256 threads -> 64(y) x 32(x) tile x 4 output channels (one group)
// thread: txg = tid&7 -> 4 consecutive x; tyg = tid>>3 -> 2 consecutive y rows
__global__ __launch_bounds__(256) void conv_k(
    const f16* __restrict__ probs, const float* __restrict__ weight,
    const float* __restrict__ bias, float* __restrict__ out) {
  const int x0  = blockIdx.x * TX;
  const int y0  = blockIdx.y * TY;
  const int b   = blockIdx.z >> 2;
  const int g   = blockIdx.z & 3;
  const int tid = threadIdx.x;
  const int txg = tid & 7;
  const int tyg = tid >> 3;       // 0..31
  const int xb  = x0 + 4 * txg;   // thread x base
  const int r0  = 2 * tyg;        // thread local row base

  // tile entirely above the diagonal -> pure zeros
  if (x0 > y0 + TY - 1) {
    const float4 z4 = make_float4(0.f, 0.f, 0.f, 0.f);
#pragma unroll
    for (int co = 0; co < 4; ++co) {
      const int c = g * 4 + co;
#pragma unroll
      for (int r = 0; r < 2; ++r) {
        const int gy = y0 + r0 + r;
        float* op = out + ((size_t)(b * C_CH + c) * L_DIM + gy) * L_DIM + xb;
        *reinterpret_cast<float4*>(op) = z4;
      }
    }
    return;
  }

  __shared__ float tile[HY * PITCH];

  float acc0[4][4];
  float acc1[4][4];
#pragma unroll
  for (int co = 0; co < 4; ++co)
#pragma unroll
    for (int j = 0; j < 4; ++j) { acc0[co][j] = 0.f; acc1[co][j] = 0.f; }

  for (int ci = 0; ci < 4; ++ci) {
    const int cin = g * C_PG + ci;
    const f16* pbase = probs + (size_t)(b * C_CH + cin) * L_DIM * L_DIM;

    __syncthreads();   // previous iteration's readers done before overwrite
    for (int idx = tid; idx < HY * HX; idx += 256) {
      const int yy = idx / HX;
      const int xx = idx - yy * HX;
      const int gy = y0 + yy - PADK;
      const int gx = x0 + xx - PADK;
      float pv = 0.f;
      if (gy >= 0 && gy < L_DIM && gx >= 0 && gx <= gy)
        pv = (float)pbase[(size_t)gy * L_DIM + gx];
      tile[yy * PITCH + xx] = pv;
    }
    __syncthreads();

    for (int ky = 0; ky < K_SZ; ++ky) {
      const float* rp0 = &tile[(r0 + ky) * PITCH + 4 * txg];
      const float* rp1 = rp0 + PITCH;
      float p0[16], p1[16];
#pragma unroll
      for (int q = 0; q < 4; ++q) {
        const float4 f0 = *reinterpret_cast<const float4*>(rp0 + 4 * q);
        p0[4*q+0] = f0.x; p0[4*q+1] = f0.y; p0[4*q+2] = f0.z; p0[4*q+3] = f0.w;
        const float4 f1 = *reinterpret_cast<const float4*>(rp1 + 4 * q);
        p1[4*q+0] = f1.x; p1[4*q+1] = f1.y; p1[4*q+2] = f1.z; p1[4*q+3] = f1.w;
      }
#pragma unroll
      for (int co = 0; co < 4; ++co) {
        // block-uniform weight indices -> scalar loads -> SGPR operand in FMA
        const float* wr = weight + ((((g * 4 + co) * C_PG + ci) * K_SZ + ky) * K_SZ);
#pragma unroll
        for (int kx = 0; kx < K_SZ; ++kx) {
          const float wv = wr[kx];
#pragma unroll
          for (int j = 0; j < 4; ++j) {
            acc0[co][j] = fmaf(wv, p0[kx + j], acc0[co][j]);
            acc1[co][j] = fmaf(wv, p1[kx + j], acc1[co][j]);
          }
        }
      }
    }
  }

  // epilogue: bias + causal re-mask, float4 stores
#pragma unroll
  for (int co = 0; co < 4; ++co) {
    const int c = g * 4 + co;
    const float bv = bias[c];
    {
      const int gy = y0 + r0;
      float4 o;
      o.x = (xb + 0 <= gy) ? acc0[co][0] + bv : 0.f;
      o.y = (xb + 1 <= gy) ? acc0[co][1] + bv : 0.f;
      o.z = (xb + 2 <= gy) ? acc0[co][2] + bv : 0.f;
      o.w = (xb + 3 <= gy) ? acc0[co][3] + bv : 0.f;
      float* op = out + ((size_t)(b * C_CH + c) * L_DIM + gy) * L_DIM + xb;
      *reinterpret_cast<float4*>(op) = o;
    }
    {
      const int gy = y0 + r0 + 1;
      float4 o;
      o.x = (xb + 0 <= gy) ? acc1[co][0] + bv : 0.f;
      o.y = (xb + 1 <= gy) ? acc1[co][1] + bv : 0.f;
      o.z = (xb + 2 <= gy) ? acc1[co][2] + bv : 0.f;
      o.w = (xb + 3 <= gy) ? acc1[co][3] + bv : 0.f;
      float* op = out + ((size_t)(b * C_CH + c) * L_DIM + gy) * L_DIM + xb;
      *reinterpret_cast<float4*>(op) = o;
    }
  }
}

extern "C" void kernel_launch(void* const* d_in, const int* in_sizes, int n_in,
                              void* d_out, int out_size, void* d_ws, size_t ws_size,
                              hipStream_t stream) {
  const float* scores = (const float*)d_in[0];
  const float* weight = (const float*)d_in[1];
  const float* bias   = (const float*)d_in[2];
  float* out = (float*)d_out;
  f16* probs = (f16*)d_ws;   // B*C*L*L fp16 = 256 MB

  // softmax: one wave per row; 65536 rows / 4 waves per block
  const int rows = B_SZ * C_CH * L_DIM;
  softmax_rows_k<<<rows / 4, 256, 0, stream>>>(scores, probs);

  // conv: 64 x-tiles, 32 y-tiles, B*G z
  dim3 grid(L_DIM / TX, L_DIM / TY, B_SZ * N_G);
  conv_k<<<grid, 256, 0, stream>>>(probs, weight, bias, out);
}

// Round 2
// 849.322 us; speedup vs baseline: 1.2725x; 1.2725x over previous
//
#include <hip/hip_runtime.h>
#include <cmath>

#define L_DIM 2048
#define C_CH  16
#define B_SZ  2
#define N_G   4
#define C_PG  4
#define K_SZ  11
#define PADK  5

#define TY 64
#define TX 32
#define HY (TY + K_SZ - 1)   /* 74 */
#define HX (TX + K_SZ - 1)   /* 42 */
#define PITCH2 44            /* u32 pitch; 44%32=12 -> benign 2-way alias */

#define WLDS_N (2 * 4 * K_SZ * 12)  /* [cp][co][ky][kx pad 12] = 1056 */

typedef _Float16 f16;
typedef __attribute__((ext_vector_type(2))) _Float16 half2v;

union U32H2 { unsigned u; half2v h; };

struct alignas(8) H4 { f16 x, y, z, w; };

__device__ __forceinline__ float dot2f(unsigned w, unsigned p, float acc) {
#if __has_builtin(__builtin_amdgcn_fdot2)
  U32H2 uw, up; uw.u = w; up.u = p;
  return __builtin_amdgcn_fdot2(uw.h, up.h, acc, false);
#else
  U32H2 uw, up; uw.u = w; up.u = p;
  acc = fmaf((float)uw.h[0], (float)up.h[0], acc);
  acc = fmaf((float)uw.h[1], (float)up.h[1], acc);
  return acc;
#endif
}

// ---------------- causal softmax: one wave per row ----------------
__global__ __launch_bounds__(256) void softmax_rows_k(
    const float* __restrict__ scores, f16* __restrict__ probs) {
  const int wid  = (blockIdx.x << 2) + (threadIdx.x >> 6);  // global row id
  const int lane = threadIdx.x & 63;
  const int y    = wid & (L_DIM - 1);                        // row within map
  const float* srow = scores + (size_t)wid * L_DIM;

  float v[32];
#pragma unroll
  for (int j = 0; j < 8; ++j) {
    const int x = j * 256 + lane * 4;
    float4 f = make_float4(-INFINITY, -INFINITY, -INFINITY, -INFINITY);
    if (x <= y)   // chunk touches the causal region -> load it
      f = *reinterpret_cast<const float4*>(srow + x);
    v[4*j+0] = (x + 0 <= y) ? f.x : -INFINITY;
    v[4*j+1] = (x + 1 <= y) ? f.y : -INFINITY;
    v[4*j+2] = (x + 2 <= y) ? f.z : -INFINITY;
    v[4*j+3] = (x + 3 <= y) ? f.w : -INFINITY;
  }
  float m = v[0];
#pragma unroll
  for (int i = 1; i < 32; ++i) m = fmaxf(m, v[i]);
#pragma unroll
  for (int off = 32; off >= 1; off >>= 1) m = fmaxf(m, __shfl_xor(m, off, 64));

  float s = 0.f;
#pragma unroll
  for (int i = 0; i < 32; ++i) { v[i] = __expf(v[i] - m); s += v[i]; }
#pragma unroll
  for (int off = 32; off >= 1; off >>= 1) s += __shfl_xor(s, off, 64);
  const float inv = 1.0f / s;

  f16* prow = probs + (size_t)wid * L_DIM;
#pragma unroll
  for (int j = 0; j < 8; ++j) {
    const int x = j * 256 + lane * 4;
    if (x > y) continue;   // conv never reads strictly-above-diagonal probs
    H4 h;
    h.x = (f16)(v[4*j+0] * inv);
    h.y = (f16)(v[4*j+1] * inv);
    h.z = (f16)(v[4*j+2] * inv);
    h.w = (f16)(v[4*j+3] * inv);
    *reinterpret_cast<H4*>(prow + x) = h;
  }
}

// ---------------- grouped 11x11 conv via packed-f16 dot2 ----------------
// block: 256 threads -> 64(y) x 32(x) tile x 4 output channels (one group)
// channels paired (ci0,ci1) in f16x2; v_dot2_f32_f16 accumulates in f32
__global__ __launch_bounds__(256) void conv_k(
    const f16* __restrict__ probs, const float* __restrict__ weight,
    const float* __restrict__ bias, float* __restrict__ out) {
  const int x0  = blockIdx.x * TX;
  const int y0  = blockIdx.y * TY;
  const int b   = blockIdx.z >> 2;
  const int g   = blockIdx.z & 3;
  const int tid = threadIdx.x;
  const int txg = tid & 7;
  const int tyg = tid >> 3;       // 0..31
  const int xb  = x0 + 4 * txg;   // thread x base
  const int r0  = 2 * tyg;        // thread local row base

  // tile entirely above the diagonal -> pure zeros
  if (x0 > y0 + TY - 1) {
    const float4 z4 = make_float4(0.f, 0.f, 0.f, 0.f);
#pragma unroll
    for (int co = 0; co < 4; ++co) {
      const int c = g * 4 + co;
#pragma unroll
      for (int r = 0; r < 2; ++r) {
        const int gy = y0 + r0 + r;
        float* op = out + ((size_t)(b * C_CH + c) * L_DIM + gy) * L_DIM + xb;
        *reinterpret_cast<float4*>(op) = z4;
      }
    }
    return;
  }

  __shared__ unsigned tile2[HY * PITCH2];
  __shared__ unsigned wlds[WLDS_N];

  // ---- pack this group's weights into LDS as (ci0,ci1) f16 pairs ----
  for (int widx = tid; widx < WLDS_N; widx += 256) {
    const int kx = widx % 12;
    const int t  = widx / 12;       // = (cp*4+co)*11 + ky
    const int ky = t % 11;
    const int t2 = t / 11;
    const int co = t2 & 3;
    const int cp = t2 >> 2;
    unsigned pk = 0;
    if (kx < 11) {
      const float* wb =
          weight + ((((size_t)(g * 4 + co) * C_PG + cp * 2) * K_SZ + ky) * K_SZ) + kx;
      U32H2 u;
      u.h = half2v{(f16)wb[0], (f16)wb[K_SZ * K_SZ]};
      pk = u.u;
    }
    wlds[widx] = pk;
  }

  float acc0[4][4];
  float acc1[4][4];
#pragma unroll
  for (int co = 0; co < 4; ++co)
#pragma unroll
    for (int j = 0; j < 4; ++j) { acc0[co][j] = 0.f; acc1[co][j] = 0.f; }

  const size_t plane = (size_t)L_DIM * L_DIM;

  for (int cp = 0; cp < 2; ++cp) {
    const f16* pa = probs + ((size_t)(b * C_CH) + g * C_PG + cp * 2) * plane;
    const f16* pb = pa + plane;

    __syncthreads();   // cp=0: weight pack done; cp=1: tile2 readers done
    {
      int yy = tid / HX;
      int xx = tid - yy * HX;
      for (int idx = tid; idx < HY * HX; idx += 256) {
        const int gy = y0 + yy - PADK;
        const int gx = x0 + xx - PADK;
        unsigned pk = 0;
        if (gy >= 0 && gy < L_DIM && gx >= 0 && gx <= gy) {
          const size_t o = (size_t)gy * L_DIM + gx;
          U32H2 u;
          u.h = half2v{pa[o], pb[o]};
          pk = u.u;
        }
        tile2[yy * PITCH2 + xx] = pk;
        yy += 6; xx += 4;              // advance by 256 = 6*42 + 4
        if (xx >= HX) { xx -= HX; yy += 1; }
      }
    }
    __syncthreads();

    for (int ky = 0; ky < K_SZ; ++ky) {
      const unsigned* rp0 = &tile2[(r0 + ky) * PITCH2 + 4 * txg];
      const unsigned* rp1 = rp0 + PITCH2;
      unsigned p0[16], p1[16];
#pragma unroll
      for (int q = 0; q < 4; ++q) {
        *reinterpret_cast<uint4*>(&p0[4 * q]) = *reinterpret_cast<const uint4*>(rp0 + 4 * q);
        *reinterpret_cast<uint4*>(&p1[4 * q]) = *reinterpret_cast<const uint4*>(rp1 + 4 * q);
      }
#pragma unroll
      for (int co = 0; co < 4; ++co) {
        const unsigned* wr = &wlds[((cp * 4 + co) * K_SZ + ky) * 12];
        unsigned wv[12];
#pragma unroll
        for (int q = 0; q < 3; ++q)
          *reinterpret_cast<uint4*>(&wv[4 * q]) = *reinterpret_cast<const uint4*>(wr + 4 * q);
#pragma unroll
        for (int kx = 0; kx < K_SZ; ++kx) {
#pragma unroll
          for (int j = 0; j < 4; ++j) {
            acc0[co][j] = dot2f(wv[kx], p0[kx + j], acc0[co][j]);
            acc1[co][j] = dot2f(wv[kx], p1[kx + j], acc1[co][j]);
          }
        }
      }
    }
  }

  // epilogue: bias + causal re-mask, float4 stores
#pragma unroll
  for (int co = 0; co < 4; ++co) {
    const int c = g * 4 + co;
    const float bv = bias[c];
    {
      const int gy = y0 + r0;
      float4 o;
      o.x = (xb + 0 <= gy) ? acc0[co][0] + bv : 0.f;
      o.y = (xb + 1 <= gy) ? acc0[co][1] + bv : 0.f;
      o.z = (xb + 2 <= gy) ? acc0[co][2] + bv : 0.f;
      o.w = (xb + 3 <= gy) ? acc0[co][3] + bv : 0.f;
      float* op = out + ((size_t)(b * C_CH + c) * L_DIM + gy) * L_DIM + xb;
      *reinterpret_cast<float4*>(op) = o;
    }
    {
      const int gy = y0 + r0 + 1;
      float4 o;
      o.x = (xb + 0 <= gy) ? acc1[co][0] + bv : 0.f;
      o.y = (xb + 1 <= gy) ? acc1[co][1] + bv : 0.f;
      o.z = (xb + 2 <= gy) ? acc1[co][2] + bv : 0.f;
      o.w = (xb + 3 <= gy) ? acc1[co][3] + bv : 0.f;
      float* op = out + ((size_t)(b * C_CH + c) * L_DIM + gy) * L_DIM + xb;
      *reinterpret_cast<float4*>(op) = o;
    }
  }
}

extern "C" void kernel_launch(void* const* d_in, const int* in_sizes, int n_in,
                              void* d_out, int out_size, void* d_ws, size_t ws_size,
                              hipStream_t stream) {
  const float* scores = (const float*)d_in[0];
  const float* weight = (const float*)d_in[1];
  const float* bias   = (const float*)d_in[2];
  float* out = (float*)d_out;
  f16* probs = (f16*)d_ws;   // B*C*L*L fp16 = 256 MB

  const int rows = B_SZ * C_CH * L_DIM;
  softmax_rows_k<<<rows / 4, 256, 0, stream>>>(scores, probs);

  dim3 grid(L_DIM / TX, L_DIM / TY, B_SZ * N_G);
  conv_k<<<grid, 256, 0, stream>>>(probs, weight, bias, out);
}

// Round 3
// 802.225 us; speedup vs baseline: 1.3472x; 1.0587x over previous
//
#include <hip/hip_runtime.h>
#include <cmath>

#define L_DIM 2048
#define C_CH  16
#define B_SZ  2
#define N_G   4
#define C_PG  4
#define K_SZ  11
#define PADK  5

#define TY 64
#define TX 32
#define HY (TY + K_SZ - 1)   /* 74 */
#define HX (TX + K_SZ - 1)   /* 42 */
#define PITCH2 44            /* u32 pitch; 4-aligned for b128, benign aliasing */

typedef _Float16 f16;
typedef __attribute__((ext_vector_type(2))) _Float16 half2v;

union U32H2 { unsigned u; half2v h; unsigned short s[2]; };

struct alignas(8) H4 { f16 x, y, z, w; };

__device__ __forceinline__ float dot2f(unsigned w, unsigned p, float acc) {
#if __has_builtin(__builtin_amdgcn_fdot2)
  U32H2 uw, up; uw.u = w; up.u = p;
  return __builtin_amdgcn_fdot2(uw.h, up.h, acc, false);
#else
  U32H2 uw, up; uw.u = w; up.u = p;
  acc = fmaf((float)uw.h[0], (float)up.h[0], acc);
  acc = fmaf((float)uw.h[1], (float)up.h[1], acc);
  return acc;
#endif
}

// ---- pack weights as (f16 lo=ci even, hi=ci odd) u32 into probs plane-0 ----
// layout: row r = g*2+cp (8 rows), each row holds [co][ky][12] = 528 u32
// placed at f16 col 32 (byte 64) of plane-0 rows 0..7 — provably untouched:
// softmax writes row y only at cols <= y+3 <= 10; conv staging reads row y
// only at cols <= y <= 7 for these rows.
__global__ void pack_w_k(const float* __restrict__ weight, f16* __restrict__ probs) {
  const int t = threadIdx.x;
  for (int idx = t; idx < 8 * 528; idx += 256) {
    const int row  = idx / 528;
    const int rem  = idx - row * 528;
    const int co   = rem / 132;
    const int rem2 = rem - co * 132;
    const int ky   = rem2 / 12;
    const int kx   = rem2 - ky * 12;
    const int g = row >> 1, cp = row & 1;
    unsigned pk = 0;
    if (kx < 11) {
      const int c = g * 4 + co;
      const float* wb = weight + (((size_t)c * C_PG + cp * 2) * K_SZ + ky) * K_SZ + kx;
      U32H2 u;
      u.h = half2v{(f16)wb[0], (f16)wb[K_SZ * K_SZ]};
      pk = u.u;
    }
    unsigned* dst = reinterpret_cast<unsigned*>(probs + (size_t)row * L_DIM + 32);
    dst[rem] = pk;
  }
}

// ---------------- causal softmax: one wave per row ----------------
__global__ __launch_bounds__(256) void softmax_rows_k(
    const float* __restrict__ scores, f16* __restrict__ probs) {
  const int wid  = (blockIdx.x << 2) + (threadIdx.x >> 6);
  const int lane = threadIdx.x & 63;
  const int y    = wid & (L_DIM - 1);
  const float* srow = scores + (size_t)wid * L_DIM;

  float v[32];
#pragma unroll
  for (int j = 0; j < 8; ++j) {
    const int x = j * 256 + lane * 4;
    float4 f = make_float4(-INFINITY, -INFINITY, -INFINITY, -INFINITY);
    if (x <= y)
      f = *reinterpret_cast<const float4*>(srow + x);
    v[4*j+0] = (x + 0 <= y) ? f.x : -INFINITY;
    v[4*j+1] = (x + 1 <= y) ? f.y : -INFINITY;
    v[4*j+2] = (x + 2 <= y) ? f.z : -INFINITY;
    v[4*j+3] = (x + 3 <= y) ? f.w : -INFINITY;
  }
  float m = v[0];
#pragma unroll
  for (int i = 1; i < 32; ++i) m = fmaxf(m, v[i]);
#pragma unroll
  for (int off = 32; off >= 1; off >>= 1) m = fmaxf(m, __shfl_xor(m, off, 64));

  float s = 0.f;
#pragma unroll
  for (int i = 0; i < 32; ++i) { v[i] = __expf(v[i] - m); s += v[i]; }
#pragma unroll
  for (int off = 32; off >= 1; off >>= 1) s += __shfl_xor(s, off, 64);
  const float inv = 1.0f / s;

  f16* prow = probs + (size_t)wid * L_DIM;
#pragma unroll
  for (int j = 0; j < 8; ++j) {
    const int x = j * 256 + lane * 4;
    if (x > y) continue;
    H4 h;
    h.x = (f16)(v[4*j+0] * inv);
    h.y = (f16)(v[4*j+1] * inv);
    h.z = (f16)(v[4*j+2] * inv);
    h.w = (f16)(v[4*j+3] * inv);
    *reinterpret_cast<H4*>(prow + x) = h;
  }
}

// ---------------- grouped 11x11 conv: dot2 + SGPR weights ----------------
// block: 256 threads -> 64(y) x 32(x) tile x 4 output channels (one group)
// thread: 1 row (tyg = tid>>2), 8 consecutive x (txg = tid&3), 4 co -> 32 acc
__global__ __launch_bounds__(256, 4) void conv_k(
    const f16* __restrict__ probs, const float* __restrict__ bias,
    float* __restrict__ out) {
  const int x0  = blockIdx.x * TX;
  const int y0  = blockIdx.y * TY;
  const int b   = blockIdx.z >> 2;
  const int g   = blockIdx.z & 3;
  const int tid = threadIdx.x;
  const int txg = tid & 3;
  const int tyg = tid >> 2;       // 0..63
  const int xb  = x0 + 8 * txg;   // thread x base
  const int gy  = y0 + tyg;       // thread output row

  // tile entirely above the diagonal -> pure zeros
  if (x0 > y0 + TY - 1) {
    const float4 z4 = make_float4(0.f, 0.f, 0.f, 0.f);
#pragma unroll
    for (int co = 0; co < 4; ++co) {
      float* op = out + ((size_t)(b * C_CH + g * 4 + co) * L_DIM + gy) * L_DIM + xb;
      *reinterpret_cast<float4*>(op) = z4;
      *reinterpret_cast<float4*>(op + 4) = z4;
    }
    return;
  }

  __shared__ unsigned tile2[2][HY * PITCH2];   // [cp][y][x] packed ci-pairs

  // ---- stage all 4 input channels (two ci-pairs) in ONE pass ----
  {
    const size_t plane = (size_t)L_DIM * L_DIM;
    const f16* p0 = probs + ((size_t)(b * C_CH) + g * C_PG) * plane;
    const f16* p1 = p0 + plane;
    const f16* p2 = p1 + plane;
    const f16* p3 = p2 + plane;
    int yy = tid / HX;
    int xx = tid - yy * HX;
    for (int idx = tid; idx < HY * HX; idx += 256) {
      const int py = y0 + yy - PADK;
      const int px = x0 + xx - PADK;
      unsigned a = 0, bpk = 0;
      if (py >= 0 && py < L_DIM && px >= 0 && px <= py) {
        const size_t o = (size_t)py * L_DIM + px;
        const unsigned short u0 = *reinterpret_cast<const unsigned short*>(p0 + o);
        const unsigned short u1 = *reinterpret_cast<const unsigned short*>(p1 + o);
        const unsigned short u2 = *reinterpret_cast<const unsigned short*>(p2 + o);
        const unsigned short u3 = *reinterpret_cast<const unsigned short*>(p3 + o);
        a   = (unsigned)u0 | ((unsigned)u1 << 16);
        bpk = (unsigned)u2 | ((unsigned)u3 << 16);
      }
      tile2[0][yy * PITCH2 + xx] = a;
      tile2[1][yy * PITCH2 + xx] = bpk;
      yy += 6; xx += 4;              // advance by 256 = 6*42 + 4
      if (xx >= HX) { xx -= HX; yy += 1; }
    }
  }
  __syncthreads();

  float acc[4][8];
#pragma unroll
  for (int co = 0; co < 4; ++co)
#pragma unroll
    for (int j = 0; j < 8; ++j) acc[co][j] = 0.f;

#pragma unroll
  for (int cp = 0; cp < 2; ++cp) {
    // packed weights: block-uniform address -> scalar loads into SGPRs
    const unsigned* pw = reinterpret_cast<const unsigned*>(
        probs + (size_t)(g * 2 + cp) * L_DIM + 32);
    const unsigned* tb = tile2[cp];

    for (int ky = 0; ky < K_SZ; ++ky) {
      const unsigned* rp = tb + (tyg + ky) * PITCH2 + 8 * txg;
      unsigned p[20];
#pragma unroll
      for (int q = 0; q < 5; ++q)
        *reinterpret_cast<uint4*>(&p[4 * q]) = *reinterpret_cast<const uint4*>(rp + 4 * q);
#pragma unroll
      for (int co = 0; co < 4; ++co) {
        const uint4* wq = reinterpret_cast<const uint4*>(pw + (co * K_SZ + ky) * 12);
        const uint4 w0 = wq[0], w1 = wq[1], w2 = wq[2];
        const unsigned wv[12] = {w0.x, w0.y, w0.z, w0.w,
                                 w1.x, w1.y, w1.z, w1.w,
                                 w2.x, w2.y, w2.z, w2.w};
#pragma unroll
        for (int kx = 0; kx < K_SZ; ++kx) {
#pragma unroll
          for (int j = 0; j < 8; ++j)
            acc[co][j] = dot2f(wv[kx], p[kx + j], acc[co][j]);
        }
      }
    }
  }

  // epilogue: bias + causal re-mask
#pragma unroll
  for (int co = 0; co < 4; ++co) {
    const float bv = bias[g * 4 + co];
    float4 o0, o1;
    o0.x = (xb + 0 <= gy) ? acc[co][0] + bv : 0.f;
    o0.y = (xb + 1 <= gy) ? acc[co][1] + bv : 0.f;
    o0.z = (xb + 2 <= gy) ? acc[co][2] + bv : 0.f;
    o0.w = (xb + 3 <= gy) ? acc[co][3] + bv : 0.f;
    o1.x = (xb + 4 <= gy) ? acc[co][4] + bv : 0.f;
    o1.y = (xb + 5 <= gy) ? acc[co][5] + bv : 0.f;
    o1.z = (xb + 6 <= gy) ? acc[co][6] + bv : 0.f;
    o1.w = (xb + 7 <= gy) ? acc[co][7] + bv : 0.f;
    float* op = out + ((size_t)(b * C_CH + g * 4 + co) * L_DIM + gy) * L_DIM + xb;
    *reinterpret_cast<float4*>(op) = o0;
    *reinterpret_cast<float4*>(op + 4) = o1;
  }
}

extern "C" void kernel_launch(void* const* d_in, const int* in_sizes, int n_in,
                              void* d_out, int out_size, void* d_ws, size_t ws_size,
                              hipStream_t stream) {
  const float* scores = (const float*)d_in[0];
  const float* weight = (const float*)d_in[1];
  const float* bias   = (const float*)d_in[2];
  float* out = (float*)d_out;
  f16* probs = (f16*)d_ws;   // B*C*L*L fp16 = 256 MB (+ packed weights in plane-0 hole)

  pack_w_k<<<1, 256, 0, stream>>>(weight, probs);

  const int rows = B_SZ * C_CH * L_DIM;
  softmax_rows_k<<<rows / 4, 256, 0, stream>>>(scores, probs);

  dim3 grid(L_DIM / TX, L_DIM / TY, B_SZ * N_G);
  conv_k<<<grid, 256, 0, stream>>>(probs, bias, out);
}